// Round 1
// baseline (525.532 us; speedup 1.0000x reference)
//
#include <hip/hip_runtime.h>

#define T_STEPS 1000
#define B_TOT   2048
#define I_IN    40
#define H_N     16
#define TC      25
#define NCHUNK  40
#define EPB     2
#define BLOCK   256
#define ELEM_LDS   (TC*48)          // 1200 floats per elem per chunk (12-slot padded quarters)
#define CHUNK_LDS  (EPB*ELEM_LDS)   // 2400 floats
#define NUNIT      (EPB*TC*10)      // 500 float4 units per chunk
#define LOGITS_OFF 1
#define CORR_OFF  (1 + 2*B_TOT*T_STEPS)   // 4096001
#define TOTAL_OFF (CORR_OFF + 1)          // 4096002

__global__ void snn_init(float* out) {
    out[0] = 0.0f;
    out[CORR_OFF] = 0.0f;
    out[TOTAL_OFF] = 1216512.0f;   // 594 flagged steps * 2048 batch
}

// quad_perm DPP helpers: pure VALU cross-lane within groups of 4
__device__ __forceinline__ float dpp_xor1(float v) {
    return __int_as_float(__builtin_amdgcn_update_dpp(0, __float_as_int(v), 0xB1, 0xF, 0xF, true));
}
__device__ __forceinline__ float dpp_xor2(float v) {
    return __int_as_float(__builtin_amdgcn_update_dpp(0, __float_as_int(v), 0x4E, 0xF, 0xF, true));
}
// row_half_mirror (0x141): lane reads lane with bits 0..2 flipped, within each
// 8-lane group. d_st is quad-uniform (bits 0-1 of lane don't affect it), so the
// fetched value is bit-identical to lane^4 — replaces ds_swizzle xor4 with a
// pure-VALU DPP op, removing the per-timestep LDS round trip from the
// recurrence critical path.
__device__ __forceinline__ float dpp_hm(float v) {
    return __int_as_float(__builtin_amdgcn_update_dpp(0, __float_as_int(v), 0x141, 0xF, 0xF, true));
}

// __launch_bounds__(256,4): 4 waves/EU -> 4 blocks/CU co-resident, which the
// 1024-block grid needs in a single pass; caps VGPR at 128.
__global__ __launch_bounds__(BLOCK, 4) void snn_main(
    const float* __restrict__ x, const int* __restrict__ target,
    const float* __restrict__ W1, const float* __restrict__ tau_m,
    const float* __restrict__ tau_n, const float* __restrict__ mask,
    const float* __restrict__ W2, const float* __restrict__ b2,
    float* __restrict__ out)
{
    __shared__ float xbuf[2][CHUNK_LDS];
    __shared__ unsigned smask[EPB*2*TC];   // [g][h][t] 8-bit spike masks
    __shared__ float w2s[2*H_N];           // W2 staged once; frees 32 VGPRs per thread

    const int tid  = threadIdx.x;
    const int g    = tid >> 7;        // batch elem within block (0..1)
    const int lane = tid & 63;
    const int h    = (tid >> 6) & 1;  // which wave of the elem (neurons 0-7 / 8-15)
    const int q    = lane & 3;        // residue class (stride-4 split of the dot product)
    const int br   = (lane >> 2) & 1; // branch
    const int nl   = lane >> 3;       // neuron-local 0..7
    const int n    = h*8 + nl;        // neuron 0..15
    const int r    = n*2 + br;        // dendritic row 0..31
    const int b0   = blockIdx.x * EPB;

    if (tid < 2*H_N) w2s[tid] = W2[tid];   // consumed after chunk-0 barriers

    // lane's residue-class weights: w[j] = Wm[r][4j+q], j=0..9 (same accumulation order as R1/R2)
    float w[10];
#pragma unroll
    for (int j = 0; j < 10; ++j) {
        const int i = 4*j + q;
        w[j] = W1[r*I_IN + i] * mask[r*I_IN + i];
    }

    const float alpha = 1.0f / (1.0f + __expf(-tau_m[n]));
    const float beta  = 1.0f / (1.0f + __expf(-tau_n[r]));
    const float b2v0  = b2[0];
    const float b2v1  = b2[1];

    // staging: unit u covers x[(b0+e), t0+tf, 4*f4 .. 4*f4+4), scattered into [t][q][12] layout
    int goff0, lds0, goff1 = 0, lds1 = 0;
    const bool v1ok = (tid + BLOCK) < NUNIT;
    {
        const int u = tid, e = u/250, rem = u%250, tf = rem/10, f4 = rem%10;
        goff0 = ((b0+e)*T_STEPS + tf)*I_IN + 4*f4;
        lds0  = e*ELEM_LDS + tf*48 + f4;
    }
    if (v1ok) {
        const int u = tid + BLOCK, e = u/250, rem = u%250, tf = rem/10, f4 = rem%10;
        goff1 = ((b0+e)*T_STEPS + tf)*I_IN + 4*f4;
        lds1  = e*ELEM_LDS + tf*48 + f4;
    }

    float4 pf0 = *(const float4*)(x + goff0);
    float4 pf1 = v1ok ? *(const float4*)(x + goff1) : make_float4(0,0,0,0);

    // combine role: CONTIGUOUS 50 lanes in wave 3 only (tid 192..241), so
    // waves 0-2 skip the whole logits/softmax/loss stream via s_cbranch_execz.
    const int  p    = tid - 192;
    const bool comb = (p >= 0) && (p < EPB*TC);

    float d_st = 0.0f, mem = 0.0f, spk = 0.0f;
    float acc_loss = 0.0f, acc_corr = 0.0f;
    unsigned long long cap = 0;

    for (int c = 0; c < NCHUNK; ++c) {
        const int t0 = c * TC;
        float* buf = xbuf[c & 1];
        // transpose-scatter staged data: component k -> quarter slot k*12
        buf[lds0] = pf0.x; buf[lds0+12] = pf0.y; buf[lds0+24] = pf0.z; buf[lds0+36] = pf0.w;
        if (v1ok) { buf[lds1] = pf1.x; buf[lds1+12] = pf1.y; buf[lds1+24] = pf1.z; buf[lds1+36] = pf1.w; }
        __syncthreads();
        if (c + 1 < NCHUNK) {
            const int tadd = (t0 + TC) * I_IN;
            pf0 = *(const float4*)(x + tadd + goff0);
            if (v1ok) pf1 = *(const float4*)(x + tadd + goff1);
        }

        const float* xg = buf + g*ELEM_LDS + q*12;
#pragma unroll
        for (int tt = 0; tt < TC; ++tt) {
            const float* xp = xg + tt*48;
            const float4 a0 = *(const float4*)(xp);
            const float4 a1 = *(const float4*)(xp + 4);
            const float2 a2 = *(const float2*)(xp + 8);
            float s = 0.0f;                       // s_q, accumulated in R1's j order
            s = fmaf(w[0], a0.x, s); s = fmaf(w[1], a0.y, s);
            s = fmaf(w[2], a0.z, s); s = fmaf(w[3], a0.w, s);
            s = fmaf(w[4], a1.x, s); s = fmaf(w[5], a1.y, s);
            s = fmaf(w[6], a1.z, s); s = fmaf(w[7], a1.w, s);
            s = fmaf(w[8], a2.x, s); s = fmaf(w[9], a2.y, s);
            const float s01 = s + dpp_xor1(s);    // (s0+s1) / (s2+s3)
            const float cur = s01 + dpp_xor2(s01);// (s0+s1)+(s2+s3): bit-exact R1 order
            d_st = fmaf(beta, d_st - cur, cur);
            const float l = d_st + dpp_hm(d_st);  // branch sum, VALU-only (was ds_swizzle)
            mem = fmaf(alpha, (mem - spk) - l, l);
            const bool fired = mem > 1.0f;
            spk = fired ? 1.0f : 0.0f;
            const unsigned long long bal = __ballot(fired);
            if (lane == tt) cap = bal;
        }

        // publish 8-bit spike masks (bit k = neuron h*8+k, from lane k*8 of the ballot)
        if (lane < TC) {
            unsigned m8 = 0;
#pragma unroll
            for (int k = 0; k < 8; ++k)
                m8 |= ((unsigned)(cap >> (k*8)) & 1u) << k;
            smask[(g*2 + h)*TC + lane] = m8;
        }
        __syncthreads();

        if (comb) {
            const int cg = p / TC, ct = p % TC;
            const int t = t0 + ct;
            const unsigned m = smask[(cg*2 + 0)*TC + ct] | (smask[(cg*2 + 1)*TC + ct] << 8);
            float sL0 = b2v0, sL1 = b2v1;
#pragma unroll
            for (int nn = 0; nn < H_N; ++nn) {     // same fma order as R2 -> bit-exact logits
                const float f = (float)((m >> nn) & 1u);
                sL0 = fmaf(f, w2s[nn], sL0);
                sL1 = fmaf(f, w2s[H_N + nn], sL1);
            }
            const int b = b0 + cg;
            const int oidx = (b*T_STEPS + t)*2;
            out[LOGITS_OFF + oidx]     = sL0;
            out[LOGITS_OFF + oidx + 1] = sL1;
            const bool flag = (t > 10) && (((t - 10) % 15) > 5);
            if (flag) {
                const int tgt = target[b*T_STEPS + t];
                float mx  = fmaxf(sL0, sL1);
                float e0  = __expf(sL0 - mx), e1 = __expf(sL1 - mx);
                float inv = 1.0f / (e0 + e1);
                float p0  = e0*inv, p1 = e1*inv;
                float mm  = fmaxf(p0, p1);
                float lse = mm + __logf(__expf(p0 - mm) + __expf(p1 - mm));
                float qv  = ((tgt == 1) ? p1 : p0) - lse;
                acc_loss -= qv;
                const int pred = (p1 > p0) ? 1 : 0;
                acc_corr += (pred == tgt) ? 1.0f : 0.0f;
            }
        }
    }

    // only wave 3 carries nonzero loss/corr now
    if (tid >= 192) {
        acc_loss *= (1.0f / (float)B_TOT);
#pragma unroll
        for (int mk = 1; mk < 64; mk <<= 1) {
            acc_loss += __shfl_xor(acc_loss, mk, 64);
            acc_corr += __shfl_xor(acc_corr, mk, 64);
        }
        if (lane == 0) {
            atomicAdd(out, acc_loss);
            atomicAdd(out + CORR_OFF, acc_corr);
        }
    }
}

extern "C" void kernel_launch(void* const* d_in, const int* in_sizes, int n_in,
                              void* d_out, int out_size, void* d_ws, size_t ws_size,
                              hipStream_t stream) {
    const float* x      = (const float*)d_in[0];
    const int*   target = (const int*)d_in[1];
    const float* W1     = (const float*)d_in[2];
    const float* tau_m  = (const float*)d_in[3];
    const float* tau_n  = (const float*)d_in[4];
    const float* mask   = (const float*)d_in[5];
    const float* W2     = (const float*)d_in[6];
    const float* b2     = (const float*)d_in[7];
    float* out = (float*)d_out;

    snn_init<<<1, 1, 0, stream>>>(out);
    snn_main<<<B_TOT/EPB, BLOCK, 0, stream>>>(x, target, W1, tau_m, tau_n, mask, W2, b2, out);
}